// Round 10
// baseline (237.990 us; speedup 1.0000x reference)
//
#include <hip/hip_runtime.h>
#include <hip/hip_bf16.h>

#define H_ 64
#define FF_ 128
#define V_ 64
#define B_ 256
#define L_ 4096

typedef __attribute__((ext_vector_type(2))) float f32x2;
typedef __attribute__((ext_vector_type(4))) int i32x4;

__device__ __forceinline__ float wsum64(float x) {
  #pragma unroll
  for (int m = 32; m; m >>= 1) x += __shfl_xor(x, m, 64);
  return x;
}
__device__ __forceinline__ float readlane_f(float x, int lane) {
  return __int_as_float(__builtin_amdgcn_readlane(__float_as_int(x), lane));
}

// ---------------------------------------------------------------------------
// Kernel 1: per-token-id tables (64 blocks x 64 threads; verified round 3)
// ---------------------------------------------------------------------------
__global__ __launch_bounds__(64) void build_tables(
    const float* __restrict__ embed, const float* __restrict__ W1,
    const float* __restrict__ b1, const float* __restrict__ W2,
    const float* __restrict__ b2, const float* __restrict__ gamma,
    const float* __restrict__ beta, const float* __restrict__ Wk,
    const float* __restrict__ Wv, const float* __restrict__ Wq,
    float2* __restrict__ kv_table, float* __restrict__ q_table)
{
  const int tok = blockIdx.x;
  const int l = threadIdx.x;
  __shared__ float sh_h[H_];
  __shared__ float sh_a[FF_];
  __shared__ float sh_n[H_];

  float h = embed[tok * H_ + l];
  sh_h[l] = h;
  __syncthreads();

  float a0 = b1[l], a1 = b1[l + 64];
  #pragma unroll 8
  for (int j = 0; j < H_; ++j) {
    float hj = sh_h[j];
    a0 = fmaf(hj, W1[j * FF_ + l], a0);
    a1 = fmaf(hj, W1[j * FF_ + l + 64], a1);
  }
  sh_a[l]      = fmaxf(a0, 0.f);
  sh_a[l + 64] = fmaxf(a1, 0.f);
  __syncthreads();

  float x = h + b2[l];
  #pragma unroll 8
  for (int f = 0; f < FF_; ++f) x = fmaf(sh_a[f], W2[f * H_ + l], x);

  float mu = wsum64(x) * (1.0f / 64.0f);
  float d = x - mu;
  float var = wsum64(d * d) * (1.0f / 64.0f);
  float hn = d * rsqrtf(var + 1e-5f) * gamma[l] + beta[l];
  sh_n[l] = hn;
  __syncthreads();

  float k = 0.f, v = 0.f, q = 0.f;
  #pragma unroll 8
  for (int i = 0; i < H_; ++i) {
    float hi = sh_n[i];
    k = fmaf(hi, Wk[i * H_ + l], k);
    v = fmaf(hi, Wv[i * H_ + l], v);
    q = fmaf(hi, Wq[i * H_ + l], q);
  }
  float n2 = wsum64(k * k);
  float kn = k / fmaxf(sqrtf(n2), 1e-12f);
  kv_table[tok * H_ + l] = make_float2(kn, v);
  q_table[tok * H_ + l] = q;
}

// ---------------------------------------------------------------------------
// Kernel 2: Gram[a][j] = kn_a . kn_j
// ---------------------------------------------------------------------------
__global__ __launch_bounds__(64) void build_gram(
    const float2* __restrict__ kv_table, float* __restrict__ gram)
{
  const int arow = blockIdx.x;
  const int j = threadIdx.x;
  float s = 0.f;
  #pragma unroll 8
  for (int i = 0; i < H_; ++i)
    s = fmaf(kv_table[arow * H_ + i].x, kv_table[j * H_ + i].x, s);
  gram[arow * H_ + j] = s;
}

// ---------------------------------------------------------------------------
// Kernel 3: backward vector scan in Gram-space.
// R9's counted-lgkmcnt asm prefetch pipeline (rows/tokens 2 phases ahead)
// + R3's group-of-4 triangular fixup in EXEC: all 4 dot-products read the
// SAME pre-group a (parallel readlanes, one hazard window), then a short
// c1->c2->c3 fixup chain and a treed rank-4 update. Serial chain per 4
// steps ~= 1 readlane + 6 dependent FMAs instead of 4x(readlane+fma).
//   exact algebra: c_g = d_g - sum_{h<g} c_h G[s_h][s_g]  (G symmetric)
// ---------------------------------------------------------------------------
#define DS64(dst, addr)  asm volatile("ds_read_b64 %0, %1"  : "=v"(dst) : "v"(addr))
#define DS128(dst, addr) asm volatile("ds_read_b128 %0, %1" : "=v"(dst) : "v"(addr))
#define LGKM(n) do { asm volatile("s_waitcnt lgkmcnt(" #n ")" ::: "memory"); \
                     __builtin_amdgcn_sched_barrier(0); } while (0)

#define PREP(S) do { \
  ss##S##0 = __builtin_amdgcn_readfirstlane(tk##S.w); \
  ss##S##1 = __builtin_amdgcn_readfirstlane(tk##S.z); \
  ss##S##2 = __builtin_amdgcn_readfirstlane(tk##S.y); \
  ss##S##3 = __builtin_amdgcn_readfirstlane(tk##S.x); \
  DS64(rb##S##0, gv_base + (unsigned)(ss##S##0) * 512u); \
  DS64(rb##S##1, gv_base + (unsigned)(ss##S##1) * 512u); \
  DS64(rb##S##2, gv_base + (unsigned)(ss##S##2) * 512u); \
  DS64(rb##S##3, gv_base + (unsigned)(ss##S##3) * 512u); \
} while (0)

#define TOKLD(S) do { \
  DS128(tk##S, atok); \
  atok = (atok >= tok_base + 16u) ? (atok - 16u) : tok_base; \
} while (0)

#define EXEC(S) do { \
  float g10 = readlane_f((rb##S##1).x, ss##S##0); \
  float g20 = readlane_f((rb##S##2).x, ss##S##0); \
  float g21 = readlane_f((rb##S##2).x, ss##S##1); \
  float g30 = readlane_f((rb##S##3).x, ss##S##0); \
  float g31 = readlane_f((rb##S##3).x, ss##S##1); \
  float g32 = readlane_f((rb##S##3).x, ss##S##2); \
  float d0 = readlane_f(a, ss##S##0); \
  float d1 = readlane_f(a, ss##S##1); \
  float d2 = readlane_f(a, ss##S##2); \
  float d3 = readlane_f(a, ss##S##3); \
  float c0 = d0; \
  float c1 = fmaf(-c0, g10, d1); \
  float c2 = fmaf(-c1, g21, fmaf(-c0, g20, d2)); \
  float c3 = fmaf(-c2, g32, fmaf(-c1, g31, fmaf(-c0, g30, d3))); \
  float pa_ = fmaf(c1, (rb##S##1).x, c0 * (rb##S##0).x); \
  float pb_ = fmaf(c3, (rb##S##3).x, c2 * (rb##S##2).x); \
  a = a - pa_ - pb_; \
  r = fmaf(c0, (rb##S##0).y, r); \
  r = fmaf(c1, (rb##S##1).y, r); \
  r = fmaf(c2, (rb##S##2).y, r); \
  r = fmaf(c3, (rb##S##3).y, r); \
} while (0)

#define PHASE(EP, PP) do { \
  LGKM(5); \
  PREP(PP); \
  TOKLD(EP); \
  LGKM(11); \
  EXEC(EP); \
} while (0)

__global__ __launch_bounds__(64) void scan_kernel(
    const int* __restrict__ seq, const float2* __restrict__ kv_table,
    const float* __restrict__ q_table, const float* __restrict__ gram,
    const float* __restrict__ Wr, const float* __restrict__ br,
    const float* __restrict__ Wo, const float* __restrict__ bo,
    float* __restrict__ out)
{
  const int b = blockIdx.x, l = threadIdx.x;
  __shared__ __align__(16) int stok[L_];   // 16 KB
  __shared__ float kn_s[64 * 65];          // padded kn rows (a-init)
  __shared__ __align__(8) float2 gv_s[64 * 64]; // (gram, v) fused rows, 32 KB
  __shared__ float qs[64], sh_r[64], sh_rr[64];

  { // stage sequence (int4)
    const int4* src = reinterpret_cast<const int4*>(seq + b * L_);
    int4* dst = reinterpret_cast<int4*>(stok);
    for (int i = l; i < 1024; i += 64) dst[i] = src[i];
  }
  // stage tables: kn (padded) + fused (gram, v)
  for (int idx = l * 2; idx < 4096; idx += 128) {
    float4 kv2 = *reinterpret_cast<const float4*>(&kv_table[idx]); // 2 float2
    float2 g2 = *reinterpret_cast<const float2*>(&gram[idx]);
    int row = idx >> 6, col = idx & 63;
    kn_s[row * 65 + col] = kv2.x;
    kn_s[row * 65 + col + 1] = kv2.z;
    gv_s[idx] = make_float2(g2.x, kv2.y);
    gv_s[idx + 1] = make_float2(g2.y, kv2.w);
  }
  __syncthreads();

  const int tq = stok[L_ - 1];
  qs[l] = q_table[tq * 64 + l];
  __syncthreads();

  // a_l = kn_vocab[l] . q
  float a = 0.f;
  #pragma unroll 8
  for (int i = 0; i < 64; ++i) a = fmaf(kn_s[l * 65 + i], qs[i], a);
  float r = 0.f;

  // 3 singles: t = 4094, 4093, 4092 (plain C; compiler-managed waits)
  const float2* gvl = gv_s + l;
  #pragma unroll
  for (int t = 4094; t >= 4092; --t) {
    int s0 = __builtin_amdgcn_readfirstlane(stok[t]);
    float2 g = gvl[s0 * 64];
    float c0 = readlane_f(a, s0);
    a = fmaf(-c0, g.x, a);
    r = fmaf(c0, g.y, r);
  }

  // ---- asm software pipeline over 1023 chunks of 4 steps ----
  unsigned tok_base = (unsigned)(size_t)stok;
  unsigned gv_base  = (unsigned)(size_t)gv_s + (unsigned)l * 8u;
  i32x4 tk0, tk1, tk2, tk3;
  f32x2 rb00, rb01, rb02, rb03, rb10, rb11, rb12, rb13,
        rb20, rb21, rb22, rb23, rb30, rb31, rb32, rb33;
  int ss00, ss01, ss02, ss03, ss10, ss11, ss12, ss13,
      ss20, ss21, ss22, ss23, ss30, ss31, ss32, ss33;

  // prologue, interleaved to match steady-state DS-queue pattern:
  // [T0 T1 | wait(0) | P0 T2 P1 T3]   (chunk c tokens at stok[4088-4c])
  DS128(tk0, tok_base + 16352u);   // chunk 0
  DS128(tk1, tok_base + 16336u);   // chunk 1
  LGKM(0);
  PREP(0);
  DS128(tk2, tok_base + 16320u);   // chunk 2
  PREP(1);
  DS128(tk3, tok_base + 16304u);   // chunk 3
  unsigned atok = tok_base + 16288u;  // phase p reads chunk p+4 at 16288-16p

  #pragma unroll 1
  for (int it = 0; it < 255; ++it) {   // phases 0..1019
    PHASE(0, 2);
    PHASE(1, 3);
    PHASE(2, 0);
    PHASE(3, 1);
  }
  PHASE(0, 2);   // phase 1020
  PHASE(1, 3);   // phase 1021
  PHASE(2, 0);   // phase 1022  (chunks 0..1022 all executed; 3+1023*4 = 4095)
  LGKM(0);       // drain stray prefetches before tail

  // tail: out = (r @ Wr + br) @ Wo + bo
  sh_r[l] = r;
  __syncthreads();
  float rr = br[l];
  #pragma unroll 8
  for (int i = 0; i < 64; ++i) rr = fmaf(sh_r[i], Wr[i * 64 + l], rr);
  sh_rr[l] = rr;
  __syncthreads();
  float o = bo[l];
  #pragma unroll 8
  for (int j = 0; j < 64; ++j) o = fmaf(sh_rr[j], Wo[j * 64 + l], o);
  out[b * V_ + l] = o;
}

extern "C" void kernel_launch(void* const* d_in, const int* in_sizes, int n_in,
                              void* d_out, int out_size, void* d_ws, size_t ws_size,
                              hipStream_t stream) {
  const int*   seq   = (const int*)  d_in[0];
  const float* embed = (const float*)d_in[1];
  const float* W1    = (const float*)d_in[2];
  const float* b1    = (const float*)d_in[3];
  const float* W2    = (const float*)d_in[4];
  const float* b2    = (const float*)d_in[5];
  const float* gamma = (const float*)d_in[6];
  const float* beta  = (const float*)d_in[7];
  const float* Wk    = (const float*)d_in[8];
  const float* Wv    = (const float*)d_in[9];
  const float* Wq    = (const float*)d_in[10];
  const float* Wr    = (const float*)d_in[11];
  const float* br    = (const float*)d_in[12];
  const float* Wo    = (const float*)d_in[13];
  const float* bo    = (const float*)d_in[14];
  float* out = (float*)d_out;

  float2* kv_table = (float2*)d_ws;                     // 32 KB
  float*  q_table  = (float*)((char*)d_ws + 32 * 1024); // 16 KB
  float*  gram     = (float*)((char*)d_ws + 48 * 1024); // 16 KB

  build_tables<<<V_, 64, 0, stream>>>(embed, W1, b1, W2, b2, gamma, beta,
                                      Wk, Wv, Wq, kv_table, q_table);
  build_gram<<<V_, 64, 0, stream>>>(kv_table, gram);
  scan_kernel<<<B_, 64, 0, stream>>>(seq, kv_table, q_table, gram,
                                     Wr, br, Wo, bo, out);
}

// Round 11
// 200.138 us; speedup vs baseline: 1.1891x; 1.1891x over previous
//
#include <hip/hip_runtime.h>
#include <hip/hip_bf16.h>

#define H_ 64
#define FF_ 128
#define V_ 64
#define B_ 256
#define L_ 4096

typedef __attribute__((ext_vector_type(2))) float f32x2;
typedef __attribute__((ext_vector_type(4))) int i32x4;

__device__ __forceinline__ float wsum64(float x) {
  #pragma unroll
  for (int m = 32; m; m >>= 1) x += __shfl_xor(x, m, 64);
  return x;
}
__device__ __forceinline__ float readlane_f(float x, int lane) {
  return __int_as_float(__builtin_amdgcn_readlane(__float_as_int(x), lane));
}

// ---------------------------------------------------------------------------
// Kernel 1: per-token-id tables (64 blocks x 64 threads; verified round 3)
// ---------------------------------------------------------------------------
__global__ __launch_bounds__(64) void build_tables(
    const float* __restrict__ embed, const float* __restrict__ W1,
    const float* __restrict__ b1, const float* __restrict__ W2,
    const float* __restrict__ b2, const float* __restrict__ gamma,
    const float* __restrict__ beta, const float* __restrict__ Wk,
    const float* __restrict__ Wv, const float* __restrict__ Wq,
    float2* __restrict__ kv_table, float* __restrict__ q_table)
{
  const int tok = blockIdx.x;
  const int l = threadIdx.x;
  __shared__ float sh_h[H_];
  __shared__ float sh_a[FF_];
  __shared__ float sh_n[H_];

  float h = embed[tok * H_ + l];
  sh_h[l] = h;
  __syncthreads();

  float a0 = b1[l], a1 = b1[l + 64];
  #pragma unroll 8
  for (int j = 0; j < H_; ++j) {
    float hj = sh_h[j];
    a0 = fmaf(hj, W1[j * FF_ + l], a0);
    a1 = fmaf(hj, W1[j * FF_ + l + 64], a1);
  }
  sh_a[l]      = fmaxf(a0, 0.f);
  sh_a[l + 64] = fmaxf(a1, 0.f);
  __syncthreads();

  float x = h + b2[l];
  #pragma unroll 8
  for (int f = 0; f < FF_; ++f) x = fmaf(sh_a[f], W2[f * H_ + l], x);

  float mu = wsum64(x) * (1.0f / 64.0f);
  float d = x - mu;
  float var = wsum64(d * d) * (1.0f / 64.0f);
  float hn = d * rsqrtf(var + 1e-5f) * gamma[l] + beta[l];
  sh_n[l] = hn;
  __syncthreads();

  float k = 0.f, v = 0.f, q = 0.f;
  #pragma unroll 8
  for (int i = 0; i < H_; ++i) {
    float hi = sh_n[i];
    k = fmaf(hi, Wk[i * H_ + l], k);
    v = fmaf(hi, Wv[i * H_ + l], v);
    q = fmaf(hi, Wq[i * H_ + l], q);
  }
  float n2 = wsum64(k * k);
  float kn = k / fmaxf(sqrtf(n2), 1e-12f);
  kv_table[tok * H_ + l] = make_float2(kn, v);
  q_table[tok * H_ + l] = q;
}

// ---------------------------------------------------------------------------
// Kernel 2: Gram[a][j] = kn_a . kn_j
// ---------------------------------------------------------------------------
__global__ __launch_bounds__(64) void build_gram(
    const float2* __restrict__ kv_table, float* __restrict__ gram)
{
  const int arow = blockIdx.x;
  const int j = threadIdx.x;
  float s = 0.f;
  #pragma unroll 8
  for (int i = 0; i < H_; ++i)
    s = fmaf(kv_table[arow * H_ + i].x, kv_table[j * H_ + i].x, s);
  gram[arow * H_ + j] = s;
}

// ---------------------------------------------------------------------------
// Kernel 3: serial backward vector scan, DEPTH-3 asm software pipeline.
//   per step: c = a[s_t]; a -= c*Gram[s_t][:]; r += c*V[s_t][:]
// Phase p: LGKM(10) [drains P(p)+T(p+3), both issued 3 phases ago];
//          PREP((p+3)%4) [rfl tokens + issue 4x ds_read_b64 rows];
//          TOKLD((p+2)%4) [issue chunk p+6 token quad];
//          EXEC(p%4) [serial 4 steps].
// Steady-state queue (oldest first) at phase p start:
//   [P(p):4, T(p+3):1, P(p+1):4, T(p+4):1, P(p+2):4, T(p+5):1] = 15
// LGKM(10) drains the oldest 5 exactly (in-order DS completion).
// Rows are consumed ~3 phases (>=225 cyc) after issue >> LDS latency.
// ---------------------------------------------------------------------------
#define DS64(dst, addr)  asm volatile("ds_read_b64 %0, %1"  : "=v"(dst) : "v"(addr))
#define DS128(dst, addr) asm volatile("ds_read_b128 %0, %1" : "=v"(dst) : "v"(addr))
#define LGKM(n) do { asm volatile("s_waitcnt lgkmcnt(" #n ")" ::: "memory"); \
                     __builtin_amdgcn_sched_barrier(0); } while (0)

#define PREP(S) do { \
  ss##S##0 = __builtin_amdgcn_readfirstlane(tk##S.w); \
  ss##S##1 = __builtin_amdgcn_readfirstlane(tk##S.z); \
  ss##S##2 = __builtin_amdgcn_readfirstlane(tk##S.y); \
  ss##S##3 = __builtin_amdgcn_readfirstlane(tk##S.x); \
  DS64(rb##S##0, gv_base + (unsigned)(ss##S##0) * 512u); \
  DS64(rb##S##1, gv_base + (unsigned)(ss##S##1) * 512u); \
  DS64(rb##S##2, gv_base + (unsigned)(ss##S##2) * 512u); \
  DS64(rb##S##3, gv_base + (unsigned)(ss##S##3) * 512u); \
} while (0)

#define TOKLD(S) do { \
  DS128(tk##S, atok); \
  atok = (atok >= tok_base + 16u) ? (atok - 16u) : tok_base; \
} while (0)

#define EXEC(S) do { \
  float d_; \
  d_ = readlane_f(a, ss##S##0); a = fmaf(-d_, (rb##S##0).x, a); r = fmaf(d_, (rb##S##0).y, r); \
  d_ = readlane_f(a, ss##S##1); a = fmaf(-d_, (rb##S##1).x, a); r = fmaf(d_, (rb##S##1).y, r); \
  d_ = readlane_f(a, ss##S##2); a = fmaf(-d_, (rb##S##2).x, a); r = fmaf(d_, (rb##S##2).y, r); \
  d_ = readlane_f(a, ss##S##3); a = fmaf(-d_, (rb##S##3).x, a); r = fmaf(d_, (rb##S##3).y, r); \
} while (0)

#define PHASE(E, P, T) do { \
  LGKM(10); \
  PREP(P); \
  TOKLD(T); \
  EXEC(E); \
} while (0)

__global__ __launch_bounds__(64) void scan_kernel(
    const int* __restrict__ seq, const float2* __restrict__ kv_table,
    const float* __restrict__ q_table, const float* __restrict__ gram,
    const float* __restrict__ Wr, const float* __restrict__ br,
    const float* __restrict__ Wo, const float* __restrict__ bo,
    float* __restrict__ out)
{
  const int b = blockIdx.x, l = threadIdx.x;
  __shared__ __align__(16) int stok[L_];   // 16 KB
  __shared__ float kn_s[64 * 65];          // padded kn rows (a-init)
  __shared__ __align__(8) float2 gv_s[64 * 64]; // (gram, v) fused rows, 32 KB
  __shared__ float qs[64], sh_r[64], sh_rr[64];

  { // stage sequence (int4)
    const int4* src = reinterpret_cast<const int4*>(seq + b * L_);
    int4* dst = reinterpret_cast<int4*>(stok);
    for (int i = l; i < 1024; i += 64) dst[i] = src[i];
  }
  // stage tables: kn (padded) + fused (gram, v)
  for (int idx = l * 2; idx < 4096; idx += 128) {
    float4 kv2 = *reinterpret_cast<const float4*>(&kv_table[idx]); // 2 float2
    float2 g2 = *reinterpret_cast<const float2*>(&gram[idx]);
    int row = idx >> 6, col = idx & 63;
    kn_s[row * 65 + col] = kv2.x;
    kn_s[row * 65 + col + 1] = kv2.z;
    gv_s[idx] = make_float2(g2.x, kv2.y);
    gv_s[idx + 1] = make_float2(g2.y, kv2.w);
  }
  __syncthreads();

  const int tq = stok[L_ - 1];
  qs[l] = q_table[tq * 64 + l];
  __syncthreads();

  // a_l = kn_vocab[l] . q
  float a = 0.f;
  #pragma unroll 8
  for (int i = 0; i < 64; ++i) a = fmaf(kn_s[l * 65 + i], qs[i], a);
  float r = 0.f;

  // 3 singles: t = 4094, 4093, 4092 (plain C; compiler-managed waits)
  const float2* gvl = gv_s + l;
  #pragma unroll
  for (int t = 4094; t >= 4092; --t) {
    int s0 = __builtin_amdgcn_readfirstlane(stok[t]);
    float2 g = gvl[s0 * 64];
    float c0 = readlane_f(a, s0);
    a = fmaf(-c0, g.x, a);
    r = fmaf(c0, g.y, r);
  }

  // ---- depth-3 asm software pipeline over 1023 chunks of 4 steps ----
  unsigned tok_base = (unsigned)(size_t)stok;
  unsigned gv_base  = (unsigned)(size_t)gv_s + (unsigned)l * 8u;
  i32x4 tk0, tk1, tk2, tk3;
  f32x2 rb00, rb01, rb02, rb03, rb10, rb11, rb12, rb13,
        rb20, rb21, rb22, rb23, rb30, rb31, rb32, rb33;
  int ss00, ss01, ss02, ss03, ss10, ss11, ss12, ss13,
      ss20, ss21, ss22, ss23, ss30, ss31, ss32, ss33;

  // prologue: C-load tokens for chunks 0..2 (chunk c at stok[4088-4c]),
  // drain, then issue [P0 T3 P1 T4 P2 T5] = steady-state queue shape.
  tk0 = *reinterpret_cast<const i32x4*>(&stok[4088]);  // chunk 0
  tk1 = *reinterpret_cast<const i32x4*>(&stok[4084]);  // chunk 1
  tk2 = *reinterpret_cast<const i32x4*>(&stok[4080]);  // chunk 2
  LGKM(0);
  PREP(0);                          // P(0)
  DS128(tk3, tok_base + 16304u);    // T(3) -> tk3
  PREP(1);                          // P(1)
  DS128(tk0, tok_base + 16288u);    // T(4) -> tk0 (chunk0 tokens already consumed)
  PREP(2);                          // P(2)
  DS128(tk1, tok_base + 16272u);    // T(5) -> tk1
  unsigned atok = tok_base + 16256u;  // phase p loads chunk p+6 at 16256-16p

  #pragma unroll 1
  for (int it = 0; it < 255; ++it) {   // phases 0..1019
    PHASE(0, 3, 2);
    PHASE(1, 0, 3);
    PHASE(2, 1, 0);
    PHASE(3, 2, 1);
  }
  PHASE(0, 3, 2);   // phase 1020
  PHASE(1, 0, 3);   // phase 1021
  PHASE(2, 1, 0);   // phase 1022  (chunks 0..1022 executed; 3+1023*4 = 4095)
  LGKM(0);          // drain stray prefetches before tail

  // tail: out = (r @ Wr + br) @ Wo + bo
  sh_r[l] = r;
  __syncthreads();
  float rr = br[l];
  #pragma unroll 8
  for (int i = 0; i < 64; ++i) rr = fmaf(sh_r[i], Wr[i * 64 + l], rr);
  sh_rr[l] = rr;
  __syncthreads();
  float o = bo[l];
  #pragma unroll 8
  for (int j = 0; j < 64; ++j) o = fmaf(sh_rr[j], Wo[j * 64 + l], o);
  out[b * V_ + l] = o;
}

extern "C" void kernel_launch(void* const* d_in, const int* in_sizes, int n_in,
                              void* d_out, int out_size, void* d_ws, size_t ws_size,
                              hipStream_t stream) {
  const int*   seq   = (const int*)  d_in[0];
  const float* embed = (const float*)d_in[1];
  const float* W1    = (const float*)d_in[2];
  const float* b1    = (const float*)d_in[3];
  const float* W2    = (const float*)d_in[4];
  const float* b2    = (const float*)d_in[5];
  const float* gamma = (const float*)d_in[6];
  const float* beta  = (const float*)d_in[7];
  const float* Wk    = (const float*)d_in[8];
  const float* Wv    = (const float*)d_in[9];
  const float* Wq    = (const float*)d_in[10];
  const float* Wr    = (const float*)d_in[11];
  const float* br    = (const float*)d_in[12];
  const float* Wo    = (const float*)d_in[13];
  const float* bo    = (const float*)d_in[14];
  float* out = (float*)d_out;

  float2* kv_table = (float2*)d_ws;                     // 32 KB
  float*  q_table  = (float*)((char*)d_ws + 32 * 1024); // 16 KB
  float*  gram     = (float*)((char*)d_ws + 48 * 1024); // 16 KB

  build_tables<<<V_, 64, 0, stream>>>(embed, W1, b1, W2, b2, gamma, beta,
                                      Wk, Wv, Wq, kv_table, q_table);
  build_gram<<<V_, 64, 0, stream>>>(kv_table, gram);
  scan_kernel<<<B_, 64, 0, stream>>>(seq, kv_table, q_table, gram,
                                     Wr, br, Wo, bo, out);
}